// Round 9
// baseline (310.046 us; speedup 1.0000x reference)
//
#include <hip/hip_runtime.h>
#include <hip/hip_fp16.h>

// SGC forward, GEMM-commuted, fp16 tables everywhere:
//   dinv[i] = rsqrt(indeg[i]+1)
//   y1  = fp16( dinv .* (x @ W1^T) )                 (gemm1: fp32 in, fp16 out)
//   h1s = fp16( dinv .* relu( dinv[d]*(sum y1[s] + y1[d]) + b1 ) )  (gather1, XCD-sliced)
//   y2  = fp16( h1s @ W2^T )                         (gemm2: fp16 in, fp16 out)
//   out = relu( dinv[d]*(sum y2[s] + y2[d]) + b2 ) @ W3^T + b3      (gather2)
// gather1 is feature-sliced by blockIdx parity: even XCDs gather the first 64B
// half-row, odd XCDs the second -> per-XCD L2 working set 12.8->6.4MB (the
// gather floor is per-XCD L2-miss fill; slicing raises the hit rate).
// Round-8 lesson: per-node W2 epilogue in the gather serializes (compiler can't
// hold the 64-VGPR tile) -> keep W2 as a separate streaming GEMM.

#define F 64
#define C 16
#define SCAN_B 1024

__device__ __forceinline__ float rl(float v, int l) {
    return __uint_as_float(__builtin_amdgcn_readlane(__float_as_uint(v), l));
}

// load 4 consecutive fp16 (8B) -> float4
__device__ __forceinline__ float4 ld_h4(const float2* base, size_t idx) {
    float2 raw = base[idx];
    __half2 lo = __builtin_bit_cast(__half2, raw.x);
    __half2 hi = __builtin_bit_cast(__half2, raw.y);
    float2 f0 = __half22float2(lo);
    float2 f1 = __half22float2(hi);
    return make_float4(f0.x, f0.y, f1.x, f1.y);
}

// load 2 consecutive fp16 (4B) -> float2
__device__ __forceinline__ float2 ld_h2(const unsigned int* base, size_t idx) {
    unsigned int raw = base[idx];
    return __half22float2(__builtin_bit_cast(__half2, raw));
}

// ---- histogram + per-edge rank (one atomic pass) ----
__global__ void degrank_kernel(const int* __restrict__ dst, int* __restrict__ deg,
                               int* __restrict__ rank, int E) {
    int i = (blockIdx.x * blockDim.x + threadIdx.x) * 4;
    if (i + 4 <= E) {
        int4 d = *(const int4*)(dst + i);
        rank[i]     = atomicAdd(&deg[d.x], 1);
        rank[i + 1] = atomicAdd(&deg[d.y], 1);
        rank[i + 2] = atomicAdd(&deg[d.z], 1);
        rank[i + 3] = atomicAdd(&deg[d.w], 1);
    } else {
        for (int k = i; k < E; ++k) rank[k] = atomicAdd(&deg[dst[k]], 1);
    }
}

// ---- exclusive scan of deg -> rowptr ----
__global__ __launch_bounds__(256) void scan1_kernel(const int* __restrict__ deg,
                                                    int* __restrict__ part,
                                                    int* __restrict__ bsum, int n) {
    __shared__ int ts[256];
    int b = blockIdx.x, t = threadIdx.x;
    int base = b * SCAN_B + t * 4;
    int v[4], sum = 0;
#pragma unroll
    for (int k = 0; k < 4; ++k) { int i = base + k; v[k] = (i < n) ? deg[i] : 0; sum += v[k]; }
    ts[t] = sum;
    __syncthreads();
    for (int off = 1; off < 256; off <<= 1) {
        int add = (t >= off) ? ts[t - off] : 0;
        __syncthreads();
        ts[t] += add;
        __syncthreads();
    }
    int run = ts[t] - sum;
#pragma unroll
    for (int k = 0; k < 4; ++k) { int i = base + k; if (i < n) part[i] = run; run += v[k]; }
    if (t == 255) bsum[b] = ts[255];
}

__global__ __launch_bounds__(256) void scan2_kernel(int* __restrict__ bsum, int nb) {
    __shared__ int ts[256];
    int t = threadIdx.x;
    int v = (t < nb) ? bsum[t] : 0;
    ts[t] = v;
    __syncthreads();
    for (int off = 1; off < 256; off <<= 1) {
        int add = (t >= off) ? ts[t - off] : 0;
        __syncthreads();
        ts[t] += add;
        __syncthreads();
    }
    if (t < nb) bsum[t] = ts[t] - v;
}

__global__ void scan3_kernel(const int* __restrict__ part, const int* __restrict__ bsum,
                             const int* __restrict__ deg, int* __restrict__ rowptr,
                             float* __restrict__ dinv, int n, int E) {
    int i = blockIdx.x * blockDim.x + threadIdx.x;
    if (i < n) {
        rowptr[i] = part[i] + bsum[i / SCAN_B];
        dinv[i] = rsqrtf((float)deg[i] + 1.0f);
    }
    if (i == 0) rowptr[n] = E;
}

// ---- atomic-free bucket fill ----
__global__ void fill_kernel(const int* __restrict__ src, const int* __restrict__ dst,
                            const int* __restrict__ rank, const int* __restrict__ rowptr,
                            int* __restrict__ csr_src, int E) {
    int i = (blockIdx.x * blockDim.x + threadIdx.x) * 4;
    if (i + 4 <= E) {
        int4 s = *(const int4*)(src + i);
        int4 d = *(const int4*)(dst + i);
        int4 r = *(const int4*)(rank + i);
        csr_src[rowptr[d.x] + r.x] = s.x;
        csr_src[rowptr[d.y] + r.y] = s.y;
        csr_src[rowptr[d.z] + r.z] = s.z;
        csr_src[rowptr[d.w] + r.w] = s.w;
    } else {
        for (int k = i; k < E; ++k) csr_src[rowptr[dst[k]] + rank[k]] = src[k];
    }
}

// ---- gemm1: y1[i][j] = fp16( scale[i] * (x[i] . W1[j]) ), fp32 input ----
__global__ __launch_bounds__(256) void gemm1_kernel(
    const float4* __restrict__ in4, const float* __restrict__ W,
    const float* __restrict__ scale, __half* __restrict__ yout, int n) {
    int tid = threadIdx.x;
    int lane = tid & 63;
    int m = lane & 15;
    float4 w[16];
#pragma unroll
    for (int t = 0; t < 16; ++t) w[t] = *(const float4*)(W + (size_t)lane * F + 4 * t);
    int gw = blockIdx.x * 4 + (tid >> 6);
    int nw = gridDim.x * 4;
    int node = gw;
    if (node >= n) return;
    float4 v = in4[(size_t)node * 16 + m];
    while (true) {
        int nxt = node + nw;
        float4 vn;
        if (nxt < n) vn = in4[(size_t)nxt * 16 + m];   // prefetch next row
        float acc = 0.0f;
#pragma unroll
        for (int t = 0; t < 16; ++t) {
            acc = fmaf(rl(v.x, t), w[t].x, acc);
            acc = fmaf(rl(v.y, t), w[t].y, acc);
            acc = fmaf(rl(v.z, t), w[t].z, acc);
            acc = fmaf(rl(v.w, t), w[t].w, acc);
        }
        acc *= scale[node];
        yout[(size_t)node * F + lane] = __float2half(acc);
        if (nxt >= n) break;
        v = vn;
        node = nxt;
    }
}

// ---- gemm2: y2[i][j] = fp16( (h1s[i] . W2[j]) ), fp16 input ----
__global__ __launch_bounds__(256) void gemm2_kernel(
    const float2* __restrict__ in2, const float* __restrict__ W,
    __half* __restrict__ yout, int n) {
    int tid = threadIdx.x;
    int lane = tid & 63;
    int m = lane & 15;
    float4 w[16];
#pragma unroll
    for (int t = 0; t < 16; ++t) w[t] = *(const float4*)(W + (size_t)lane * F + 4 * t);
    int gw = blockIdx.x * 4 + (tid >> 6);
    int nw = gridDim.x * 4;
    int node = gw;
    if (node >= n) return;
    float4 v = ld_h4(in2, (size_t)node * 16 + m);
    while (true) {
        int nxt = node + nw;
        float4 vn;
        if (nxt < n) vn = ld_h4(in2, (size_t)nxt * 16 + m);   // prefetch
        float acc = 0.0f;
#pragma unroll
        for (int t = 0; t < 16; ++t) {
            acc = fmaf(rl(v.x, t), w[t].x, acc);
            acc = fmaf(rl(v.y, t), w[t].y, acc);
            acc = fmaf(rl(v.z, t), w[t].z, acc);
            acc = fmaf(rl(v.w, t), w[t].w, acc);
        }
        yout[(size_t)node * F + lane] = __float2half(acc);
        if (nxt >= n) break;
        v = vn;
        node = nxt;
    }
}

// ---- gather1: XCD-sliced half-row gather of y1 -> h1s (fp16) ----
// slice s = blockIdx&1 -> features [32s, 32s+32) = one 64B line per row.
// quarter-wave (16 lanes) per node; lane m holds 2 features (one dword).
__global__ __launch_bounds__(256) void gather1_kernel(
    const unsigned int* __restrict__ y, const int* __restrict__ rowptr,
    const int* __restrict__ csr_src, const float* __restrict__ dinv,
    const float* __restrict__ b1, unsigned int* __restrict__ h1s, int n) {
    int tid = threadIdx.x;
    int m = tid & 15;
    int s = blockIdx.x & 1;
    int g = blockIdx.x >> 1;
    int fo = 16 * s + m;                 // dword offset within 32-dword row
    float2 bias = *(const float2*)(b1 + 32 * s + 2 * m);
    int qid = g * 16 + (tid >> 4);
    int nq = (gridDim.x >> 1) << 4;
    for (int node = qid; node < n; node += nq) {
        int beg = rowptr[node], end = rowptr[node + 1];
        float2 a0 = {0, 0}, a1 = {0, 0}, a2 = {0, 0}, a3 = {0, 0};
        int p = beg;
        for (; p + 8 <= end; p += 8) {
            int s0 = csr_src[p],     s1 = csr_src[p + 1];
            int s2 = csr_src[p + 2], s3 = csr_src[p + 3];
            int s4 = csr_src[p + 4], s5 = csr_src[p + 5];
            int s6 = csr_src[p + 6], s7 = csr_src[p + 7];
            float2 v0 = ld_h2(y, (size_t)s0 * 32 + fo);
            float2 v1 = ld_h2(y, (size_t)s1 * 32 + fo);
            float2 v2 = ld_h2(y, (size_t)s2 * 32 + fo);
            float2 v3 = ld_h2(y, (size_t)s3 * 32 + fo);
            float2 v4 = ld_h2(y, (size_t)s4 * 32 + fo);
            float2 v5 = ld_h2(y, (size_t)s5 * 32 + fo);
            float2 v6 = ld_h2(y, (size_t)s6 * 32 + fo);
            float2 v7 = ld_h2(y, (size_t)s7 * 32 + fo);
            a0.x += v0.x + v4.x; a0.y += v0.y + v4.y;
            a1.x += v1.x + v5.x; a1.y += v1.y + v5.y;
            a2.x += v2.x + v6.x; a2.y += v2.y + v6.y;
            a3.x += v3.x + v7.x; a3.y += v3.y + v7.y;
        }
        if (p + 4 <= end) {
            int s0 = csr_src[p], s1 = csr_src[p + 1], s2 = csr_src[p + 2], s3 = csr_src[p + 3];
            float2 v0 = ld_h2(y, (size_t)s0 * 32 + fo);
            float2 v1 = ld_h2(y, (size_t)s1 * 32 + fo);
            float2 v2 = ld_h2(y, (size_t)s2 * 32 + fo);
            float2 v3 = ld_h2(y, (size_t)s3 * 32 + fo);
            a0.x += v0.x; a0.y += v0.y;
            a1.x += v1.x; a1.y += v1.y;
            a2.x += v2.x; a2.y += v2.y;
            a3.x += v3.x; a3.y += v3.y;
            p += 4;
        }
        for (; p < end; ++p) {
            int sv = csr_src[p];
            float2 v = ld_h2(y, (size_t)sv * 32 + fo);
            a0.x += v.x; a0.y += v.y;
        }
        a0.x += a1.x + a2.x + a3.x;
        a0.y += a1.y + a2.y + a3.y;
        float dd = dinv[node];
        float2 self = ld_h2(y, (size_t)node * 32 + fo);
        float2 r;
        r.x = dd * fmaxf(fmaf(dd, a0.x + self.x, bias.x), 0.0f);
        r.y = dd * fmaxf(fmaf(dd, a0.y + self.y, bias.y), 0.0f);
        h1s[(size_t)node * 32 + fo] =
            __builtin_bit_cast(unsigned int, __float22half2_rn(make_float2(r.x, r.y)));
    }
}

// ---- gather2: quarter-wave full-row gather of y2 + b2/relu + W3 (shfl) -> out ----
__global__ __launch_bounds__(256) void gather2_kernel(
    const float2* __restrict__ y, const int* __restrict__ rowptr,
    const int* __restrict__ csr_src, const float* __restrict__ dinv,
    const float* __restrict__ b2, const float* __restrict__ W3,
    const float* __restrict__ b3, float* __restrict__ out, int n) {
    int tid = threadIdx.x;
    int lane = tid & 63;
    int m = lane & 15;
    int qbase = lane & 48;
    float4 bias = *(const float4*)(b2 + 4 * m);
    float b3r = b3[m];
    int qid = (blockIdx.x * 256 + tid) >> 4;
    int nq = (gridDim.x * 256) >> 4;
    for (int node = qid; node < n; node += nq) {
        int beg = rowptr[node], end = rowptr[node + 1];
        float4 a0 = {0, 0, 0, 0}, a1 = {0, 0, 0, 0}, a2 = {0, 0, 0, 0}, a3 = {0, 0, 0, 0};
        int p = beg;
        for (; p + 8 <= end; p += 8) {
            int s0 = csr_src[p],     s1 = csr_src[p + 1];
            int s2 = csr_src[p + 2], s3 = csr_src[p + 3];
            int s4 = csr_src[p + 4], s5 = csr_src[p + 5];
            int s6 = csr_src[p + 6], s7 = csr_src[p + 7];
            float4 v0 = ld_h4(y, (size_t)s0 * 16 + m);
            float4 v1 = ld_h4(y, (size_t)s1 * 16 + m);
            float4 v2 = ld_h4(y, (size_t)s2 * 16 + m);
            float4 v3 = ld_h4(y, (size_t)s3 * 16 + m);
            float4 v4 = ld_h4(y, (size_t)s4 * 16 + m);
            float4 v5 = ld_h4(y, (size_t)s5 * 16 + m);
            float4 v6 = ld_h4(y, (size_t)s6 * 16 + m);
            float4 v7 = ld_h4(y, (size_t)s7 * 16 + m);
            a0.x += v0.x + v4.x; a0.y += v0.y + v4.y; a0.z += v0.z + v4.z; a0.w += v0.w + v4.w;
            a1.x += v1.x + v5.x; a1.y += v1.y + v5.y; a1.z += v1.z + v5.z; a1.w += v1.w + v5.w;
            a2.x += v2.x + v6.x; a2.y += v2.y + v6.y; a2.z += v2.z + v6.z; a2.w += v2.w + v6.w;
            a3.x += v3.x + v7.x; a3.y += v3.y + v7.y; a3.z += v3.z + v7.z; a3.w += v3.w + v7.w;
        }
        if (p + 4 <= end) {
            int s0 = csr_src[p], s1 = csr_src[p + 1], s2 = csr_src[p + 2], s3 = csr_src[p + 3];
            float4 v0 = ld_h4(y, (size_t)s0 * 16 + m);
            float4 v1 = ld_h4(y, (size_t)s1 * 16 + m);
            float4 v2 = ld_h4(y, (size_t)s2 * 16 + m);
            float4 v3 = ld_h4(y, (size_t)s3 * 16 + m);
            a0.x += v0.x; a0.y += v0.y; a0.z += v0.z; a0.w += v0.w;
            a1.x += v1.x; a1.y += v1.y; a1.z += v1.z; a1.w += v1.w;
            a2.x += v2.x; a2.y += v2.y; a2.z += v2.z; a2.w += v2.w;
            a3.x += v3.x; a3.y += v3.y; a3.z += v3.z; a3.w += v3.w;
            p += 4;
        }
        for (; p < end; ++p) {
            int s = csr_src[p];
            float4 v = ld_h4(y, (size_t)s * 16 + m);
            a0.x += v.x; a0.y += v.y; a0.z += v.z; a0.w += v.w;
        }
        a0.x += a1.x + a2.x + a3.x;
        a0.y += a1.y + a2.y + a3.y;
        a0.z += a1.z + a2.z + a3.z;
        a0.w += a1.w + a2.w + a3.w;
        float dd = dinv[node];
        float4 self = ld_h4(y, (size_t)node * 16 + m);
        float4 h;   // lane m of quarter: h2 features [4m..4m+3]
        h.x = fmaxf(fmaf(dd, a0.x + self.x, bias.x), 0.0f);
        h.y = fmaxf(fmaf(dd, a0.y + self.y, bias.y), 0.0f);
        h.z = fmaxf(fmaf(dd, a0.z + self.z, bias.z), 0.0f);
        h.w = fmaxf(fmaf(dd, a0.w + self.w, bias.w), 0.0f);
        // out[node][m] = b3[m] + sum_t dot(h2[4t..4t+3], W3[m][4t..4t+3])
        float acc = 0.0f;
#pragma unroll
        for (int t = 0; t < 16; ++t) {
            float4 wv = *(const float4*)(W3 + (size_t)m * F + 4 * t);   // L1-hot
            float hx = __shfl(h.x, qbase + t);
            float hy = __shfl(h.y, qbase + t);
            float hz = __shfl(h.z, qbase + t);
            float hw = __shfl(h.w, qbase + t);
            acc = fmaf(hx, wv.x, fmaf(hy, wv.y, fmaf(hz, wv.z, fmaf(hw, wv.w, acc))));
        }
        out[(size_t)node * C + m] = acc + b3r;
    }
}

extern "C" void kernel_launch(void* const* d_in, const int* in_sizes, int n_in,
                              void* d_out, int out_size, void* d_ws, size_t ws_size,
                              hipStream_t stream) {
    const float* x  = (const float*)d_in[0];
    const int* edge = (const int*)d_in[1];
    const float* W1 = (const float*)d_in[2];
    const float* b1 = (const float*)d_in[3];
    const float* W2 = (const float*)d_in[4];
    const float* b2 = (const float*)d_in[5];
    const float* W3 = (const float*)d_in[6];
    const float* b3 = (const float*)d_in[7];
    float* out = (float*)d_out;

    int n = in_sizes[0] / F;        // 100000
    int E = in_sizes[1] / 2;        // 1600000
    const int* src = edge;
    const int* dst = edge + E;

    int nb = (n + SCAN_B - 1) / SCAN_B;

    char* ws = (char*)d_ws;
    size_t o = 0;
    auto alloc = [&](size_t bytes) { char* p = ws + o; o += (bytes + 255) & ~(size_t)255; return p; };
    int*    deg     = (int*)   alloc((size_t)n * 4);
    int*    rank    = (int*)   alloc((size_t)E * 4);
    int*    part    = (int*)   alloc((size_t)n * 4);
    int*    bsum    = (int*)   alloc(256 * 4);
    int*    rowptr  = (int*)   alloc((size_t)(n + 1) * 4);
    int*    csr_src = (int*)   alloc((size_t)E * 4);
    float*  dinv    = (float*) alloc((size_t)n * 4);
    __half* y1      = (__half*)alloc((size_t)n * F * 2);   // reused as y2
    __half* h1s     = (__half*)alloc((size_t)n * F * 2);
    __half* y2      = y1;                                   // y1 dead after gather1

    hipMemsetAsync(deg, 0, (size_t)n * 4, stream);
    degrank_kernel<<<(E / 4 + 255) / 256, 256, 0, stream>>>(dst, deg, rank, E);

    scan1_kernel<<<nb, 256, 0, stream>>>(deg, part, bsum, n);
    scan2_kernel<<<1, 256, 0, stream>>>(bsum, nb);
    scan3_kernel<<<(n + 255) / 256, 256, 0, stream>>>(part, bsum, deg, rowptr, dinv, n, E);

    // y1 = fp16( dinv .* (x @ W1^T) )
    gemm1_kernel<<<2048, 256, 0, stream>>>((const float4*)x, W1, dinv, y1, n);

    fill_kernel<<<(E / 4 + 255) / 256, 256, 0, stream>>>(src, dst, rank, rowptr, csr_src, E);

    // gather1: XCD-sliced (slice = blockIdx&1)
    gather1_kernel<<<2048, 256, 0, stream>>>(
        (const unsigned int*)y1, rowptr, csr_src, dinv, b1, (unsigned int*)h1s, n);

    // y2 = fp16( h1s @ W2^T )
    gemm2_kernel<<<2048, 256, 0, stream>>>((const float2*)h1s, W2, y2, n);

    gather2_kernel<<<2048, 256, 0, stream>>>(
        (const float2*)y2, rowptr, csr_src, dinv, b2, W3, b3, out, n);
}